// Round 12
// baseline (70.703 us; speedup 1.0000x reference)
//
#include <hip/hip_runtime.h>
#include <hip/hip_bf16.h>
#include <math.h>

#define EPS 1e-8f

typedef __attribute__((ext_vector_type(8))) short short8;
typedef __attribute__((ext_vector_type(4))) float floatx4;
typedef unsigned short ushort_t;

#define GPTR(p) ((const __attribute__((address_space(1))) void*)(p))
#define LPTR(p) ((__attribute__((address_space(3))) void*)(p))

__device__ __forceinline__ unsigned short f2bf(float f) {
  unsigned int u = __float_as_uint(f);
  u += 0x7FFFu + ((u >> 16) & 1u);   // RNE
  return (unsigned short)(u >> 16);
}
__device__ __forceinline__ unsigned int pack2bf(float a, float b) {
  return (unsigned int)f2bf(a) | ((unsigned int)f2bf(b) << 16);
}

// ---- kA: one speaker per block. x -> x_bf, row norms (xx, rxn),
//          column sums -> sums_bf, ss, rcn. Single 96MB pass over x.
__global__ __launch_bounds__(256) void kA(const float* __restrict__ x,
    ushort_t* __restrict__ xbf, ushort_t* __restrict__ sums_bf,
    float* __restrict__ ss, float* __restrict__ rcn,
    float* __restrict__ xx, float* __restrict__ rxn,
    const float* __restrict__ wp) {
  const int n = blockIdx.x;
  const int t = threadIdx.x;
  const int wv = t >> 6, l = t & 63;
  __shared__ float csum[4][768];   // 12 KB
  float4 cs0 = {0,0,0,0}, cs1 = {0,0,0,0}, cs2 = {0,0,0,0};

  for (int r = 0; r < 16; ++r) {
    const int row = wv * 16 + r;
    const size_t base = ((size_t)n * 64 + row) * 768;
    const float* rp = x + base;
    float4 v0 = *(const float4*)(rp + l * 4);
    float4 v1 = *(const float4*)(rp + l * 4 + 256);
    float4 v2 = *(const float4*)(rp + l * 4 + 512);
    uint2 b0 = { pack2bf(v0.x, v0.y), pack2bf(v0.z, v0.w) };
    uint2 b1 = { pack2bf(v1.x, v1.y), pack2bf(v1.z, v1.w) };
    uint2 b2 = { pack2bf(v2.x, v2.y), pack2bf(v2.z, v2.w) };
    *(uint2*)(xbf + base + l * 4)       = b0;
    *(uint2*)(xbf + base + l * 4 + 256) = b1;
    *(uint2*)(xbf + base + l * 4 + 512) = b2;
    float rq = v0.x*v0.x + v0.y*v0.y + v0.z*v0.z + v0.w*v0.w
             + v1.x*v1.x + v1.y*v1.y + v1.z*v1.z + v1.w*v1.w
             + v2.x*v2.x + v2.y*v2.y + v2.z*v2.z + v2.w*v2.w;
    for (int o = 32; o; o >>= 1) rq += __shfl_xor(rq, o, 64);
    if (l == 0) {
      const int j = n * 64 + row;
      xx[j] = rq;
      rxn[j] = 1.0f / fmaxf(sqrtf(rq), EPS);
    }
    cs0.x += v0.x; cs0.y += v0.y; cs0.z += v0.z; cs0.w += v0.w;
    cs1.x += v1.x; cs1.y += v1.y; cs1.z += v1.z; cs1.w += v1.w;
    cs2.x += v2.x; cs2.y += v2.y; cs2.z += v2.z; cs2.w += v2.w;
  }
  *(float4*)&csum[wv][l * 4]       = cs0;
  *(float4*)&csum[wv][l * 4 + 256] = cs1;
  *(float4*)&csum[wv][l * 4 + 512] = cs2;
  __syncthreads();

  float lss = 0.f;
#pragma unroll
  for (int q = 0; q < 3; ++q) {
    const int c = t + q * 256;
    const float s = csum[0][c] + csum[1][c] + csum[2][c] + csum[3][c];
    sums_bf[(size_t)n * 768 + c] = f2bf(s);
    lss += s * s;
  }
  for (int o = 32; o; o >>= 1) lss += __shfl_xor(lss, o, 64);
  __syncthreads();
  if (l == 0) csum[1][wv] = lss;   // reuse LDS slot
  __syncthreads();
  if (t == 0) {
    const float v = csum[1][0] + csum[1][1] + csum[1][2] + csum[1][3];
    ss[n] = v;
    rcn[n] = (*wp) / fmaxf(sqrtf(v), 64.f * EPS);   // w / (M * cn)
  }
}

// ---- kC v5: 256n x 256j tile, 256 blocks (1/CU), 8 waves of 128n x 64j.
// One barrier + counted vmcnt(8) per step (3-deep prefetch, 4 buffers).
// NO intra-step lgkmcnt drain: plain ds_reads + register dataflow let the
// compiler emit fine-grained lgkmcnt and interleave MFMAs with read tail.
__global__ __launch_bounds__(512, 2) void kC(const ushort_t* __restrict__ xbf,
    const ushort_t* __restrict__ sums_bf, const float* __restrict__ rcn,
    const float* __restrict__ rxn, float* __restrict__ colsum,
    float* __restrict__ sdiag_dot, const float* __restrict__ bp) {
  __shared__ ushort_t lds[4][16384];   // 4 x 32KB: [A frags 0..15 | B frags 0..15]
  const int b = blockIdx.x;
  const int xcd = b & 7;
  const int inner = b >> 3;            // 0..31
  const int nt = inner & 1;            // n-tile twins of a j-tile share an XCD
  const int jt = xcd + ((inner >> 1) << 3);   // 0..127
  const int n0 = nt * 256, j0 = jt * 256;
  const int t = threadIdx.x, wv = t >> 6, l = t & 63;
  const int wm = wv >> 2, wj = wv & 3; // 2(m) x 4(j) wave grid; wave = 128n x 64j

// stage K-step KS_ into buffer BUF_: 4 gload_lds per thread (2 A + 2 B)
#define STAGE(KS_, BUF_) {                                                     \
    const int k0_ = (KS_) * 32;                                                \
    const ushort_t* As_ = sums_bf + (size_t)(n0 + wv * 16 + (l & 15)) * 768 +  \
                          k0_ + (l >> 4) * 8;                                  \
    const ushort_t* Bs_ = xbf + (size_t)(j0 + wv * 16 + (l & 15)) * 768 +      \
                          k0_ + (l >> 4) * 8;                                  \
    __builtin_amdgcn_global_load_lds(GPTR(As_),                                \
        LPTR(&lds[BUF_][wv * 512]), 16, 0, 0);                                 \
    __builtin_amdgcn_global_load_lds(GPTR(As_ + (size_t)128 * 768),            \
        LPTR(&lds[BUF_][(wv + 8) * 512]), 16, 0, 0);                           \
    __builtin_amdgcn_global_load_lds(GPTR(Bs_),                                \
        LPTR(&lds[BUF_][8192 + wv * 512]), 16, 0, 0);                          \
    __builtin_amdgcn_global_load_lds(GPTR(Bs_ + (size_t)128 * 768),            \
        LPTR(&lds[BUF_][8192 + (wv + 8) * 512]), 16, 0, 0);                    \
  }

  floatx4 acc[8][4];
#pragma unroll
  for (int mi = 0; mi < 8; ++mi)
#pragma unroll
    for (int ni = 0; ni < 4; ++ni) acc[mi][ni] = (floatx4){0.f, 0.f, 0.f, 0.f};

  STAGE(0, 0)
  STAGE(1, 1)
  STAGE(2, 2)                          // 12 loads/thread outstanding

  for (int kb = 0; kb < 24; ++kb) {
    if (kb < 22)       { asm volatile("s_waitcnt vmcnt(8)" ::: "memory"); }
    else if (kb == 22) { asm volatile("s_waitcnt vmcnt(4)" ::: "memory"); }
    else               { asm volatile("s_waitcnt vmcnt(0)" ::: "memory"); }
    __builtin_amdgcn_s_barrier();
    __builtin_amdgcn_sched_barrier(0);   // keep ds_reads below the barrier
    const int cb = kb & 3, sb = (kb + 3) & 3;

    short8 af[8], bf[4];
#pragma unroll
    for (int ni = 0; ni < 4; ++ni)
      bf[ni] = *(const short8*)&lds[cb][8192 + (wj * 4 + ni) * 512 + l * 8];
#pragma unroll
    for (int mi = 0; mi < 8; ++mi)
      af[mi] = *(const short8*)&lds[cb][(wm * 8 + mi) * 512 + l * 8];
    if (kb + 3 < 24) STAGE(kb + 3, sb)
    // no lgkmcnt(0): compiler inserts fine-grained waits, overlapping the
    // read tail with the first MFMAs.
    __builtin_amdgcn_s_setprio(1);
#pragma unroll
    for (int mi = 0; mi < 8; ++mi)
#pragma unroll
      for (int ni = 0; ni < 4; ++ni)
        acc[mi][ni] = __builtin_amdgcn_mfma_f32_16x16x32_bf16(
            af[mi], bf[ni], acc[mi][ni], 0, 0, 0);
    __builtin_amdgcn_s_setprio(0);
  }

  // ---- epilogue: S = acc * rcn[n] * rxn[j] + b ; colsum += exp(S); diag sx.
  const float bb = *bp;
  float rxv[4], p[4] = {0.f, 0.f, 0.f, 0.f};
#pragma unroll
  for (int ni = 0; ni < 4; ++ni)
    rxv[ni] = rxn[j0 + wj * 64 + ni * 16 + (l & 15)];
  const bool diagblk = (nt == (jt >> 6));

#pragma unroll
  for (int mi = 0; mi < 8; ++mi) {
    float4 rr = *(const float4*)&rcn[n0 + wm * 128 + mi * 16 + ((l >> 4) << 2)];
    const float rc[4] = {rr.x, rr.y, rr.z, rr.w};
#pragma unroll
    for (int ni = 0; ni < 4; ++ni) {
      floatx4 a = acc[mi][ni];
#pragma unroll
      for (int q = 0; q < 4; ++q)
        p[ni] += __expf(a[q] * rc[q] * rxv[ni] + bb);
      if (diagblk) {
        const int jg = j0 + wj * 64 + ni * 16 + (l & 15);
#pragma unroll
        for (int q = 0; q < 4; ++q) {
          const int mg = n0 + wm * 128 + mi * 16 + ((l >> 4) << 2) + q;
          if (mg == (jg >> 6)) sdiag_dot[jg] = a[q];
        }
      }
    }
  }
#pragma unroll
  for (int ni = 0; ni < 4; ++ni) {
    p[ni] += __shfl_xor(p[ni], 16, 64);
    p[ni] += __shfl_xor(p[ni], 32, 64);
  }
  if (l < 16) {
#pragma unroll
    for (int ni = 0; ni < 4; ++ni)
      atomicAdd(&colsum[j0 + wj * 64 + ni * 16 + l], p[ni]);
  }
}

// ---- kD: per-sample loss from colsum + diagonal dot, reduce to scalar -----
__global__ __launch_bounds__(256) void kD(const float* __restrict__ colsum,
    const float* __restrict__ sdiag_dot, const float* __restrict__ xx,
    const float* __restrict__ ss, const float* __restrict__ rcn,
    const float* __restrict__ wp, const float* __restrict__ bp,
    float* __restrict__ out) {
  const int j = blockIdx.x * 256 + threadIdx.x;
  const int i = j >> 6;
  const float ww = *wp, bb = *bp;
  const float sx = sdiag_dot[j];
  const float xxv = xx[j];
  const float xn = fmaxf(sqrtf(xxv), EPS);
  const float rx = 1.0f / xn;
  const float sd = sx * rcn[i] * rx + bb;                         // S_diag
  const float exn = sqrtf(fmaxf(ss[i] - 2.f * sx + xxv, 0.f)) * (1.f / 63.f);
  const float edot = (sx - xxv) * (1.f / 63.f);
  const float sm = ww * edot / (fmaxf(exn, EPS) * xn) + bb;       // S_same
  const float tot = colsum[j] - __expf(sd) + __expf(sm);
  float L = -sm + logf(fmaxf(tot, 1e-30f));
  for (int o = 32; o; o >>= 1) L += __shfl_xor(L, o, 64);
  __shared__ float red[4];
  if ((threadIdx.x & 63) == 0) red[threadIdx.x >> 6] = L;
  __syncthreads();
  if (threadIdx.x == 0) atomicAdd(out, red[0] + red[1] + red[2] + red[3]);
}

extern "C" void kernel_launch(void* const* d_in, const int* in_sizes, int n_in,
                              void* d_out, int out_size, void* d_ws, size_t ws_size,
                              hipStream_t stream) {
  const float* x  = (const float*)d_in[0];
  const float* wp = (const float*)d_in[1];
  const float* bp = (const float*)d_in[2];
  float* out = (float*)d_out;

  // ws layout (float offsets):
  float* fws = (float*)d_ws;
  float* ss        = fws;             // 512
  float* rcn       = fws + 512;       // 512
  float* xx        = fws + 1024;      // 32768
  float* rxn       = fws + 33792;     // 32768
  float* colsum    = fws + 66560;     // 32768
  float* sdiag_dot = fws + 99328;     // 32768
  ushort_t* sums_bf = (ushort_t*)(fws + 132096);   // 393216 ushorts
  ushort_t* xbf     = (ushort_t*)(fws + 328704);   // 25165824 ushorts
  // total = 12911616 floats ~= 49.3 MiB

  hipMemsetAsync(colsum, 0, 32768 * sizeof(float), stream);
  hipMemsetAsync(out, 0, sizeof(float), stream);

  kA<<<512, 256, 0, stream>>>(x, xbf, sums_bf, ss, rcn, xx, rxn, wp);
  kC<<<256, 512, 0, stream>>>(xbf, sums_bf, rcn, rxn, colsum, sdiag_dot, bp);
  kD<<<128, 256, 0, stream>>>(colsum, sdiag_dot, xx, ss, rcn, wp, bp, out);
}